// Round 12
// baseline (432.832 us; speedup 1.0000x reference)
//
#include <hip/hip_runtime.h>
#include <hip/hip_cooperative_groups.h>
#include <cmath>

namespace cg = cooperative_groups;

#define LL   4096
#define HWD  64
#define CCH  96
#define QQ   24
#define DDI  192
#define NST  16
#define NCH  128     // chunks in scan
#define CLEN 32      // steps per chunk = one LDS tile
#define TSC  32
#define XT2  32      // positions per block in k_xdbl
#define XP   108     // padded LDS stride (96-wide tiles)
#define FP   100     // fuse/final [px][c] stride
#define VP   204     // outproj [px][192ch] stride

// ---------------- workspace layout (floats) ----------------
static const size_t OFF_F    = 0;          // 786432  f (concat arf) -> reused as edge
static const size_t OFF_H    = 786432;     // 786432  h
static const size_t OFF_E    = 1572864;    // 196608  e (raw)
static const size_t OFF_E1PS = 1769472;    // 768
static const size_t OFF_E1P2 = 1770240;    // 768
static const size_t OFF_XM   = 2556736;    // 1572864 xm (B,L,192)
static const size_t OFF_Z    = 4129600;    // 1572864 z  (B,L,192)
static const size_t OFF_XC   = 5702464;    // 1572864 xc (B,L,192)
static const size_t OFF_DTS  = 7275328;    // dtr (B,K,L,6)
static const size_t OFF_BC   = 13566784;   // 1048576 B|C (B,K,L,32)
static const size_t OFF_YK   = 14615360;   // 6291456 yk (B,K,L,192)
static const size_t OFF_Y2   = 22528832;   // 786432  y2 (B,96,L)
static const size_t OFF_HL   = 23315264;   // 3145728
static const size_t OFF_SD   = 26460992;   // 196608
static const size_t OFF_HIN  = 26657600;   // 3145728
static const size_t OFF_S1PS = 29803328;   // 192*16
static const size_t OFF_S1PM = 29806400;   // 192*16
static const size_t OFF_S2PS = 29809472;   // 192*64
static const size_t OFF_S2PM = 29821760;   // 192*64

static __device__ __forceinline__ int map_k(int k, int l) {
  int ll = (k & 2) ? (LL - 1 - l) : l;
  return (k & 1) ? (((ll & 63) << 6) | (ll >> 6)) : ll;
}

// ---------------- K1: ARF grouped dilated convs ----------------
__global__ __launch_bounds__(256) void k_arf(const float* __restrict__ x,
    const float* __restrict__ w1, const float* __restrict__ b1,
    const float* __restrict__ w2, const float* __restrict__ b2,
    const float* __restrict__ w3, const float* __restrict__ b3,
    const float* __restrict__ w4, const float* __restrict__ b4,
    float* __restrict__ f) {
  int idx = blockIdx.x * 256 + threadIdx.x;
  int p = idx & (LL - 1);
  int oc = __builtin_amdgcn_readfirstlane((idx >> 12) % CCH);
  int b  = __builtin_amdgcn_readfirstlane(idx / (CCH * LL));
  int i = oc / QQ, q = oc % QQ;
  int dil = 1 << i;
  const float* w  = (i == 0 ? w1 : i == 1 ? w2 : i == 2 ? w3 : w4) + q * 36;
  const float* bb = (i == 0 ? b1 : i == 1 ? b2 : i == 2 ? b3 : b4);
  int yy0 = p >> 6, xx0 = p & 63;
  float acc = bb[q];
  const float* xin = x + ((size_t)b * CCH + q * 4) * LL;
  #pragma unroll
  for (int ky = 0; ky < 3; ky++) {
    int yy = yy0 + (ky - 1) * dil;
    if (yy < 0 || yy >= HWD) continue;
    #pragma unroll
    for (int kx = 0; kx < 3; kx++) {
      int xx = xx0 + (kx - 1) * dil;
      if (xx < 0 || xx >= HWD) continue;
      int pp = (yy << 6) + xx;
      #pragma unroll
      for (int ci = 0; ci < 4; ci++)
        acc += w[ci * 9 + ky * 3 + kx] * xin[(size_t)ci * LL + pp];
    }
  }
  f[idx] = acc;
}

// ---------------- K2: fuse 1x1 (96->96), LDS-tiled GEMM ----------------
__global__ __launch_bounds__(256) void k_fuse(const float* __restrict__ f,
    const float* __restrict__ fw, const float* __restrict__ fb, float* __restrict__ h) {
  int pix0 = blockIdx.x * 64;
  int oc0 = blockIdx.y * 48;
  int b = pix0 >> 12, p0 = pix0 & (LL - 1);
  int t = threadIdx.x;
  __shared__ float fs[64][FP];
  __shared__ float wbuf[48 * 96];
  for (int i = t; i < 96 * 16; i += 256) {
    int c = i >> 4, q = i & 15;
    float4 v = *(const float4*)(f + ((size_t)b * CCH + c) * LL + p0 + q * 4);
    fs[q * 4 + 0][c] = v.x; fs[q * 4 + 1][c] = v.y;
    fs[q * 4 + 2][c] = v.z; fs[q * 4 + 3][c] = v.w;
  }
  {
    const float4* src = (const float4*)(fw + (size_t)oc0 * CCH);
    float4* dst = (float4*)wbuf;
    for (int i = t; i < 48 * 24; i += 256) dst[i] = src[i];
  }
  __syncthreads();
  int px = t & 63;
  int cg2 = __builtin_amdgcn_readfirstlane(t >> 6);
  float acc[12];
  #pragma unroll
  for (int j = 0; j < 12; j++) acc[j] = 0.f;
  for (int c4 = 0; c4 < 24; c4++) {
    float4 xv = *(const float4*)(&fs[px][c4 * 4]);
    #pragma unroll
    for (int j = 0; j < 12; j++) {
      float4 wv = *(const float4*)(&wbuf[(cg2 * 12 + j) * 96 + c4 * 4]);
      acc[j] = fmaf(xv.x, wv.x, fmaf(xv.y, wv.y, fmaf(xv.z, wv.z, fmaf(xv.w, wv.w, acc[j]))));
    }
  }
  __syncthreads();
  float* ot = &fs[0][0];
  #pragma unroll
  for (int j = 0; j < 12; j++) ot[px * 49 + cg2 * 12 + j] = acc[j];
  __syncthreads();
  for (int i = t; i < 48 * 64; i += 256) {
    int o = i >> 6, p2 = i & 63;
    h[((size_t)b * CCH + oc0 + o) * LL + p0 + p2] = ot[p2 * 49 + o] + fb[oc0 + o];
  }
}

// ---------------- K3: depthwise 3x3 (edge) ----------------
__global__ __launch_bounds__(256) void k_edge(const float* __restrict__ h,
    const float* __restrict__ ew, float* __restrict__ edge) {
  int idx = blockIdx.x * 256 + threadIdx.x;
  int p = idx & (LL - 1);
  int c = __builtin_amdgcn_readfirstlane((idx >> 12) % CCH);
  int b = __builtin_amdgcn_readfirstlane(idx / (CCH * LL));
  int yy0 = p >> 6, xx0 = p & 63;
  const float* w = ew + c * 9;
  const float* hr = h + ((size_t)b * CCH + c) * LL;
  float acc = 0.f;
  #pragma unroll
  for (int ky = 0; ky < 3; ky++) {
    int yy = yy0 + ky - 1;
    if (yy < 0 || yy >= HWD) continue;
    #pragma unroll
    for (int kx = 0; kx < 3; kx++) {
      int xx = xx0 + kx - 1;
      if (xx < 0 || xx >= HWD) continue;
      acc += w[ky * 3 + kx] * hr[(yy << 6) + xx];
    }
  }
  edge[idx] = acc;
}

// ---------------- K4: 1x1 96->24 + BN partials ----------------
__global__ __launch_bounds__(256) void k_e1(const float* __restrict__ edge,
    const float* __restrict__ w, const float* __restrict__ bias, float* __restrict__ e,
    float* __restrict__ e1ps, float* __restrict__ e1p2) {
  int tid = threadIdx.x;
  int idx = blockIdx.x * 256 + tid;
  int p = idx & (LL - 1);
  int q = __builtin_amdgcn_readfirstlane((idx >> 12) % QQ);
  int b = __builtin_amdgcn_readfirstlane(idx / (QQ * LL));
  const float* er = edge + (size_t)b * CCH * LL + p;
  const float* wr = w + q * CCH;
  float acc = bias[q];
  for (int c = 0; c < CCH; c++) acc += wr[c] * er[(size_t)c * LL];
  e[idx] = acc;
  __shared__ float rs[256], r2[256];
  rs[tid] = acc; r2[tid] = acc * acc; __syncthreads();
  for (int st = 128; st > 0; st >>= 1) {
    if (tid < st) { rs[tid] += rs[tid + st]; r2[tid] += r2[tid + st]; }
    __syncthreads();
  }
  if (tid == 0) { e1ps[blockIdx.x] = rs[0]; e1p2[blockIdx.x] = r2[0]; }
}

// ---------------- K6: BN-reduce + enh gate + s1 partials ----------------
__global__ __launch_bounds__(256) void k_enh(const float* __restrict__ e,
    const float* __restrict__ e1ps, const float* __restrict__ e1p2,
    const float* __restrict__ bn_g, const float* __restrict__ bn_b,
    const float* __restrict__ w2, const float* __restrict__ b2,
    float* __restrict__ h, float* __restrict__ s1ps, float* __restrict__ s1pm) {
  int tid = threadIdx.x;
  __shared__ float bns[QQ], bnsh[QQ];
  if (tid < QQ) {
    float s = 0.f, s2 = 0.f;
    #pragma unroll
    for (int b2 = 0; b2 < 2; b2++)
      for (int i = 0; i < 16; i++) {
        int pi = (b2 * QQ + tid) * 16 + i;
        s += e1ps[pi]; s2 += e1p2[pi];
      }
    float mu = s / (2.f * LL);
    float var = s2 / (2.f * LL) - mu * mu;
    float sc = bn_g[tid] * rsqrtf(var + 1e-5f);
    bns[tid] = sc;
    bnsh[tid] = bn_b[tid] - mu * sc;
  }
  __syncthreads();
  int idx = blockIdx.x * 256 + tid;
  int p = idx & (LL - 1);
  int o = __builtin_amdgcn_readfirstlane((idx >> 12) % CCH);
  int b = __builtin_amdgcn_readfirstlane(idx / (CCH * LL));
  const float* er = e + (size_t)b * QQ * LL + p;
  const float* wr = w2 + o * QQ;
  float acc = b2[o];
  #pragma unroll
  for (int q = 0; q < QQ; q++) {
    float en = fmaxf(er[(size_t)q * LL] * bns[q] + bnsh[q], 0.f);
    acc += wr[q] * en;
  }
  float sig = 1.f / (1.f + __expf(-acc));
  float val = h[idx] * (1.f + sig);
  h[idx] = val;
  __shared__ float rsum[256], rmax[256];
  rsum[tid] = val; rmax[tid] = val; __syncthreads();
  for (int st = 128; st > 0; st >>= 1) {
    if (tid < st) { rsum[tid] += rsum[tid + st]; rmax[tid] = fmaxf(rmax[tid], rmax[tid + st]); }
    __syncthreads();
  }
  if (tid == 0) {
    int row = blockIdx.x >> 4, blk = blockIdx.x & 15;
    s1ps[row * 16 + blk] = rsum[0];
    s1pm[row * 16 + blk] = rmax[0];
  }
}

// ---------------- K8: fused s1-reduce + recal-FC + recal + LN + in_proj ----------------
__global__ __launch_bounds__(256) void k_inproj(const float* __restrict__ h,
    const float* __restrict__ s1ps, const float* __restrict__ s1pm,
    const float* __restrict__ fc1, const float* __restrict__ fc2,
    const float* __restrict__ ng, const float* __restrict__ nb,
    const float* __restrict__ W, float* __restrict__ xm, float* __restrict__ z) {
  int pix0 = blockIdx.x * 64;
  int oc0 = blockIdx.y * CCH;
  int b = pix0 >> 12, p0 = pix0 & (LL - 1);
  int t = threadIdx.x;
  __shared__ float xs[64][XP];
  __shared__ float wbuf[CCH * CCH];
  __shared__ float wsm[CCH];
  __shared__ float hid[QQ];
  __shared__ float ps[64][4], ps2[64][4];
  __shared__ float mu_s[64], rs_s[64];
  if (t < CCH) {
    const float4* sp = (const float4*)(s1ps + (size_t)(b * CCH + t) * 16);
    const float4* mp = (const float4*)(s1pm + (size_t)(b * CCH + t) * 16);
    float s = 0.f, m = -3.402823466e38f;
    #pragma unroll
    for (int i = 0; i < 4; i++) {
      float4 a = sp[i]; s += a.x + a.y + a.z + a.w;
      float4 c = mp[i]; m = fmaxf(m, fmaxf(fmaxf(c.x, c.y), fmaxf(c.z, c.w)));
    }
    wsm[t] = s / (float)LL + m;
  }
  __syncthreads();
  if (t < QQ) {
    float a = 0.f;
    for (int c = 0; c < CCH; c++) a += wsm[c] * fc1[t * CCH + c];
    hid[t] = fmaxf(a, 0.f);
  }
  __syncthreads();
  float w1v = 0.f;
  if (t < CCH) {
    float a = 0.f;
    #pragma unroll
    for (int q = 0; q < QQ; q++) a += hid[q] * fc2[t * QQ + q];
    w1v = 1.f / (1.f + __expf(-a));
  }
  __syncthreads();
  if (t < CCH) wsm[t] = w1v;
  {
    const float4* src = (const float4*)(W + (size_t)oc0 * CCH);
    float4* dst = (float4*)wbuf;
    for (int i = t; i < CCH * 24; i += 256) dst[i] = src[i];
  }
  __syncthreads();
  for (int i = t; i < CCH * 16; i += 256) {
    int c = i >> 4, q = i & 15;
    float w = wsm[c];
    float4 v = *(const float4*)(h + ((size_t)b * CCH + c) * LL + p0 + q * 4);
    xs[q * 4 + 0][c] = v.x * w; xs[q * 4 + 1][c] = v.y * w;
    xs[q * 4 + 2][c] = v.z * w; xs[q * 4 + 3][c] = v.w * w;
  }
  __syncthreads();
  {
    int px = t & 63, qr = t >> 6;
    float s = 0.f, s2 = 0.f;
    #pragma unroll
    for (int j = 0; j < 24; j++) { float v = xs[px][qr * 24 + j]; s += v; s2 += v * v; }
    ps[px][qr] = s; ps2[px][qr] = s2;
  }
  __syncthreads();
  if (t < 64) {
    float ss = ps[t][0] + ps[t][1] + ps[t][2] + ps[t][3];
    float ss2 = ps2[t][0] + ps2[t][1] + ps2[t][2] + ps2[t][3];
    float mu = ss / (float)CCH;
    mu_s[t] = mu;
    rs_s[t] = rsqrtf(ss2 / (float)CCH - mu * mu + 1e-5f);
  }
  __syncthreads();
  for (int i = t; i < 64 * CCH; i += 256) {
    int px = i / CCH, c = i % CCH;
    xs[px][c] = (xs[px][c] - mu_s[px]) * rs_s[px] * ng[c] + nb[c];
  }
  __syncthreads();
  int li = t & 63;
  int cg2 = __builtin_amdgcn_readfirstlane(t >> 6);
  float acc[24];
  #pragma unroll
  for (int j = 0; j < 24; j++) acc[j] = 0.f;
  for (int dq = 0; dq < 24; dq++) {
    float4 xv = *(const float4*)(&xs[li][dq * 4]);
    #pragma unroll
    for (int j = 0; j < 24; j++) {
      float4 wv = *(const float4*)(&wbuf[(cg2 + 4 * j) * CCH + dq * 4]);
      acc[j] = fmaf(xv.x, wv.x, fmaf(xv.y, wv.y, fmaf(xv.z, wv.z, fmaf(xv.w, wv.w, acc[j]))));
    }
  }
  __syncthreads();
  float* ot = &xs[0][0];
  #pragma unroll
  for (int j = 0; j < 24; j++) ot[li * 97 + cg2 + 4 * j] = acc[j];
  __syncthreads();
  float* dst = (oc0 < DDI) ? xm : z;
  int od0 = oc0 % DDI;
  for (int i = t; i < 64 * 96; i += 256) {
    int row = i / 96, c = i % 96;
    dst[(size_t)(pix0 + row) * DDI + od0 + c] = ot[row * 97 + c];
  }
}

// ---------------- K9: depthwise 3x3 + silu, 2 rows/thread ----------------
__global__ __launch_bounds__(256) void k_ssconv(const float* __restrict__ xm,
    const float* __restrict__ w, const float* __restrict__ bias, float* __restrict__ xc) {
  int idx = blockIdx.x * 256 + threadIdx.x;
  int d = idx % DDI;
  int rem = idx / DDI;
  int xx0 = rem & 63;
  int y0 = ((rem >> 6) & 31) * 2;
  int b = idx / (DDI * LL / 2);
  float wv[9];
  #pragma unroll
  for (int i = 0; i < 9; i++) wv[i] = w[d * 9 + i];
  float acc0 = bias[d], acc1 = bias[d];
  const float* xr = xm + (size_t)b * LL * DDI + d;
  #pragma unroll
  for (int ky = -1; ky <= 2; ky++) {
    int yy = y0 + ky;
    if (yy < 0 || yy >= HWD) continue;
    #pragma unroll
    for (int kx = -1; kx <= 1; kx++) {
      int xx = xx0 + kx;
      if (xx < 0 || xx >= HWD) continue;
      float val = xr[(size_t)((yy << 6) + xx) * DDI];
      if (ky <= 1) acc0 += wv[(ky + 1) * 3 + (kx + 1)] * val;
      if (ky >= 0) acc1 += wv[ky * 3 + (kx + 1)] * val;
    }
  }
  size_t o0 = ((size_t)b * LL + (y0 << 6) + xx0) * DDI + d;
  xc[o0] = acc0 / (1.f + __expf(-acc0));
  xc[o0 + 64 * DDI] = acc1 / (1.f + __expf(-acc1));
}

// ---------------- K10: x_proj (192->38) -> dtr + B/C ----------------
__global__ __launch_bounds__(256) void k_xdbl(const float* __restrict__ xc,
    const float* __restrict__ xpw, float* __restrict__ dtr_ws, float* __restrict__ bcb) {
  int lt = blockIdx.x;
  int bk = blockIdx.y;
  int b = bk >> 2, k = bk & 3;
  int t = threadIdx.x;
  __shared__ float xs[XT2][XP];
  __shared__ float wbuf[38 * 96];
  int l0 = lt * XT2;
  int pos = t & 31;
  int cg2 = t >> 5;
  float acc[5];
  #pragma unroll
  for (int j = 0; j < 5; j++) acc[j] = 0.f;
  for (int h = 0; h < 2; h++) {
    __syncthreads();
    for (int i = t; i < XT2 * 24; i += 256) {
      int row = i / 24, dq = i % 24;
      int p = map_k(k, l0 + row);
      *(float4*)(&xs[row][dq * 4]) =
          *(const float4*)(xc + ((size_t)b * LL + p) * DDI + h * 96 + dq * 4);
    }
    for (int i = t; i < 38 * 24; i += 256) {
      int c = i / 24, dq = i % 24;
      *(float4*)(&wbuf[c * 96 + dq * 4]) =
          *(const float4*)(xpw + ((size_t)k * 38 + c) * DDI + h * 96 + dq * 4);
    }
    __syncthreads();
    for (int dq = 0; dq < 24; dq++) {
      float4 xv = *(const float4*)(&xs[pos][dq * 4]);
      #pragma unroll
      for (int j = 0; j < 5; j++) {
        int c = cg2 + 8 * j;
        if (c < 38) {
          float4 wv = *(const float4*)(&wbuf[c * 96 + dq * 4]);
          acc[j] = fmaf(xv.x, wv.x, fmaf(xv.y, wv.y, fmaf(xv.z, wv.z, fmaf(xv.w, wv.w, acc[j]))));
        }
      }
    }
  }
  #pragma unroll
  for (int j = 0; j < 5; j++) {
    int c = cg2 + 8 * j;
    if (c < 6) dtr_ws[((size_t)bk * LL + l0 + pos) * 6 + c] = acc[j];
    else if (c < 38) bcb[((size_t)bk * LL + l0 + pos) * 32 + (c - 6)] = acc[j];
  }
}

// ---------------- K11: cooperative fused scan (pass0 + carry + pass1) ----------------
__global__ __launch_bounds__(192) void k_scan_all(const float* __restrict__ dtr_ws,
    const float* __restrict__ bcb, const float* __restrict__ xc,
    const float* __restrict__ A_logs, const float* __restrict__ dtw,
    const float* __restrict__ dtb, float* __restrict__ hl, float* __restrict__ sd,
    float* __restrict__ hin, float* __restrict__ yk) {
  int ch = blockIdx.x, bk = blockIdx.y;
  int b = bk >> 2, k = bk & 3;
  int d = threadIdx.x;
  __shared__ float u_s[TSC][DDI];
  __shared__ float bcs[TSC][32];
  __shared__ float dtr_s[TSC][6];
  float Av[NST];
  #pragma unroll
  for (int n = 0; n < NST; n++) Av[n] = -__expf(A_logs[(size_t)(k * DDI + d) * NST + n]);
  bool pw = true;
  #pragma unroll
  for (int n = 1; n < NST; n++) pw = pw && (fabsf(Av[n] - (float)(n + 1) * Av[0]) <= 1e-3f * (n + 1));
  float wdt[6];
  #pragma unroll
  for (int r = 0; r < 6; r++) wdt[r] = dtw[((size_t)(k * DDI + d)) * 6 + r];
  float bdt = dtb[k * DDI + d];
  int l0 = ch * CLEN;
  // ---- stage tiles (persist in LDS across grid syncs) ----
  for (int i = d; i < TSC * (DDI / 4); i += 192) {
    int row = i / (DDI / 4), q = i % (DDI / 4);
    int p = map_k(k, l0 + row);
    ((float4*)u_s)[i] = *(const float4*)(xc + ((size_t)b * LL + p) * DDI + q * 4);
  }
  {
    const float4* src = (const float4*)(bcb + ((size_t)bk * LL + l0) * 32);
    float4* dst = (float4*)bcs;
    for (int i = d; i < TSC * 32 / 4; i += 192) dst[i] = src[i];
  }
  for (int i = d; i < TSC * 6; i += 192)
    ((float*)dtr_s)[i] = dtr_ws[((size_t)bk * LL + l0) * 6 + i];
  __syncthreads();
  // ---- phase A: pass 0 (local states) ----
  float h[NST];
  #pragma unroll
  for (int n = 0; n < NST; n++) h[n] = 0.f;
  float sumdt = 0.f;
  for (int tt = 0; tt < TSC; tt++) {
    float a = bdt;
    #pragma unroll
    for (int r = 0; r < 6; r++) a = fmaf(wdt[r], dtr_s[tt][r], a);
    float dt = (a > 15.f) ? a : __logf(1.f + __expf(a));
    float dtu = dt * u_s[tt][d];
    sumdt += dt;
    float eA[NST];
    if (pw) {
      float E = __expf(dt * Av[0]);
      float en = 1.f;
      #pragma unroll
      for (int n = 0; n < NST; n++) { en *= E; eA[n] = en; }
    } else {
      #pragma unroll
      for (int n = 0; n < NST; n++) eA[n] = __expf(dt * Av[n]);
    }
    #pragma unroll
    for (int n = 0; n < NST; n++) h[n] = eA[n] * h[n] + dtu * bcs[tt][n];
  }
  {
    float* hp = hl + ((size_t)(bk * DDI + d) * NCH + ch) * NST;
    #pragma unroll
    for (int n = 0; n < NST; n++) hp[n] = h[n];
    sd[(size_t)(bk * DDI + d) * NCH + ch] = sumdt;
  }
  cg::this_grid().sync();
  // ---- phase B: carry propagation (first 24576 threads) ----
  {
    int fb = blockIdx.y * gridDim.x + blockIdx.x;
    int tg = fb * 192 + d;
    if (tg < 8 * DDI * NST) {
      int n = tg & 15;
      int d2 = (tg >> 4) % DDI;
      int bk2 = tg / (DDI * NST);
      int k2 = bk2 & 3;
      float Aval = -__expf(A_logs[(size_t)(k2 * DDI + d2) * NST + n]);
      float hh = 0.f;
      size_t base = (size_t)(bk2 * DDI + d2) * NCH;
      for (int c2 = 0; c2 < NCH; c2++) {
        hin[(base + c2) * NST + n] = hh;
        hh = __expf(Aval * sd[base + c2]) * hh + hl[(base + c2) * NST + n];
      }
    }
  }
  cg::this_grid().sync();
  // ---- phase C: pass 1 with incoming state (tiles still in LDS) ----
  {
    const float* hp = hin + ((size_t)(bk * DDI + d) * NCH + ch) * NST;
    #pragma unroll
    for (int n = 0; n < NST; n++) h[n] = hp[n];
  }
  for (int tt = 0; tt < TSC; tt++) {
    float a = bdt;
    #pragma unroll
    for (int r = 0; r < 6; r++) a = fmaf(wdt[r], dtr_s[tt][r], a);
    float dt = (a > 15.f) ? a : __logf(1.f + __expf(a));
    float dtu = dt * u_s[tt][d];
    float eA[NST];
    if (pw) {
      float E = __expf(dt * Av[0]);
      float en = 1.f;
      #pragma unroll
      for (int n = 0; n < NST; n++) { en *= E; eA[n] = en; }
    } else {
      #pragma unroll
      for (int n = 0; n < NST; n++) eA[n] = __expf(dt * Av[n]);
    }
    float y = 0.f;
    #pragma unroll
    for (int n = 0; n < NST; n++) {
      h[n] = eA[n] * h[n] + dtu * bcs[tt][n];
      y += h[n] * bcs[tt][16 + n];
    }
    int p = map_k(k, l0 + tt);
    yk[((size_t)bk * LL + p) * DDI + d] = y;
  }
}

// ---------------- K12: fused combine+LN+gate + out_proj + s2 partials ----------------
__global__ __launch_bounds__(256) void k_outproj(const float* __restrict__ yk,
    const float* __restrict__ xc, const float* __restrict__ Ds, const float* __restrict__ z,
    const float* __restrict__ ong, const float* __restrict__ onb,
    const float* __restrict__ W, float* __restrict__ y2,
    float* __restrict__ s2ps, float* __restrict__ s2pm) {
  int pix0 = blockIdx.x * 64;
  int oc0 = blockIdx.y * 48;
  int b = pix0 >> 12, p0 = pix0 & (LL - 1);
  int t = threadIdx.x;
  __shared__ float xs[64][VP];
  __shared__ float wbuf[48 * 96];
  __shared__ float dsum[DDI];
  __shared__ float ps[64][4], ps2[64][4];
  __shared__ float mu_s[64], rs_s[64];
  if (t < 48) {
    float4 a  = *(const float4*)(Ds + t * 4);
    float4 c1 = *(const float4*)(Ds + DDI + t * 4);
    float4 c2 = *(const float4*)(Ds + 2 * DDI + t * 4);
    float4 c3 = *(const float4*)(Ds + 3 * DDI + t * 4);
    *(float4*)(&dsum[t * 4]) = make_float4(a.x + c1.x + c2.x + c3.x, a.y + c1.y + c2.y + c3.y,
                                           a.z + c1.z + c2.z + c3.z, a.w + c1.w + c2.w + c3.w);
  }
  __syncthreads();
  int px = t & 63, qr = t >> 6;
  int p = p0 + px;
  size_t pb = ((size_t)b * LL + p) * DDI;
  size_t yb = ((size_t)b * 4 * LL + p) * DDI;
  {
    float s = 0.f, s2 = 0.f;
    #pragma unroll
    for (int j = 0; j < 12; j++) {
      int c = (qr * 12 + j) * 4;
      float4 y0 = *(const float4*)(yk + yb + c);
      float4 y1 = *(const float4*)(yk + yb + (size_t)LL * DDI + c);
      float4 y2v = *(const float4*)(yk + yb + 2ul * LL * DDI + c);
      float4 y3 = *(const float4*)(yk + yb + 3ul * LL * DDI + c);
      float4 u = *(const float4*)(xc + pb + c);
      float4 dv = *(const float4*)(&dsum[c]);
      float4 v;
      v.x = y0.x + y1.x + y2v.x + y3.x + dv.x * u.x;
      v.y = y0.y + y1.y + y2v.y + y3.y + dv.y * u.y;
      v.z = y0.z + y1.z + y2v.z + y3.z + dv.z * u.z;
      v.w = y0.w + y1.w + y2v.w + y3.w + dv.w * u.w;
      *(float4*)(&xs[px][c]) = v;
      s += v.x + v.y + v.z + v.w;
      s2 += v.x * v.x + v.y * v.y + v.z * v.z + v.w * v.w;
    }
    ps[px][qr] = s; ps2[px][qr] = s2;
  }
  __syncthreads();
  if (t < 64) {
    float ss = ps[t][0] + ps[t][1] + ps[t][2] + ps[t][3];
    float ss2 = ps2[t][0] + ps2[t][1] + ps2[t][2] + ps2[t][3];
    float mu = ss / (float)DDI;
    mu_s[t] = mu;
    rs_s[t] = rsqrtf(ss2 / (float)DDI - mu * mu + 1e-5f);
  }
  __syncthreads();
  {
    float mu = mu_s[px], rs = rs_s[px];
    #pragma unroll
    for (int j = 0; j < 12; j++) {
      int c = (qr * 12 + j) * 4;
      float4 v = *(const float4*)(&xs[px][c]);
      float4 zz = *(const float4*)(z + pb + c);
      float4 og = *(const float4*)(ong + c);
      float4 ob = *(const float4*)(onb + c);
      float4 gv;
      gv.x = ((v.x - mu) * rs * og.x + ob.x) * (zz.x / (1.f + __expf(-zz.x)));
      gv.y = ((v.y - mu) * rs * og.y + ob.y) * (zz.y / (1.f + __expf(-zz.y)));
      gv.z = ((v.z - mu) * rs * og.z + ob.z) * (zz.z / (1.f + __expf(-zz.z)));
      gv.w = ((v.w - mu) * rs * og.w + ob.w) * (zz.w / (1.f + __expf(-zz.w)));
      *(float4*)(&xs[px][c]) = gv;
    }
  }
  int li = px;
  int cg2 = __builtin_amdgcn_readfirstlane(qr);
  float acc[12];
  #pragma unroll
  for (int j = 0; j < 12; j++) acc[j] = 0.f;
  for (int hh = 0; hh < 2; hh++) {
    __syncthreads();
    for (int i = t; i < 48 * 24; i += 256) {
      int c = i / 24, dq = i % 24;
      *(float4*)(&wbuf[c * 96 + dq * 4]) =
          *(const float4*)(W + (size_t)(oc0 + c) * DDI + hh * 96 + dq * 4);
    }
    __syncthreads();
    for (int dq = 0; dq < 24; dq++) {
      float4 xv = *(const float4*)(&xs[li][hh * 96 + dq * 4]);
      #pragma unroll
      for (int j = 0; j < 12; j++) {
        float4 wv = *(const float4*)(&wbuf[(cg2 + 4 * j) * 96 + dq * 4]);
        acc[j] = fmaf(xv.x, wv.x, fmaf(xv.y, wv.y, fmaf(xv.z, wv.z, fmaf(xv.w, wv.w, acc[j]))));
      }
    }
  }
  int lane = t & 63;
  #pragma unroll
  for (int j = 0; j < 12; j++) {
    float sv = acc[j], mv = acc[j];
    #pragma unroll
    for (int o = 32; o > 0; o >>= 1) {
      sv += __shfl_xor(sv, o);
      mv = fmaxf(mv, __shfl_xor(mv, o));
    }
    if (lane == 0) {
      int oc = oc0 + cg2 + 4 * j;
      int tile = blockIdx.x & 63;
      s2ps[(size_t)(b * CCH + oc) * 64 + tile] = sv;
      s2pm[(size_t)(b * CCH + oc) * 64 + tile] = mv;
    }
  }
  __syncthreads();
  float* ot = &xs[0][0];
  #pragma unroll
  for (int j = 0; j < 12; j++) ot[li * 49 + cg2 + 4 * j] = acc[j];
  __syncthreads();
  for (int i = t; i < 48 * 64; i += 256) {
    int o = i / 64, pi = i % 64;
    y2[((size_t)b * CCH + oc0 + o) * LL + p0 + pi] = ot[pi * 49 + o];
  }
}

// ---------------- K14: fused s2-reduce + recal-FC + recal + proj + residual ----------------
__global__ __launch_bounds__(256) void k_final(const float* __restrict__ x,
    const float* __restrict__ y2, const float* __restrict__ s2ps, const float* __restrict__ s2pm,
    const float* __restrict__ fc1, const float* __restrict__ fc2,
    const float* __restrict__ pw, const float* __restrict__ pb, float* __restrict__ out) {
  int pix0 = blockIdx.x * 64;
  int oc0 = blockIdx.y * 48;
  int b = pix0 >> 12, p0 = pix0 & (LL - 1);
  int t = threadIdx.x;
  __shared__ float fs[64][FP];
  __shared__ float wbuf[48 * 96];
  __shared__ float wsm[CCH];
  __shared__ float hid[QQ];
  if (t < CCH) {
    const float4* sp = (const float4*)(s2ps + (size_t)(b * CCH + t) * 64);
    const float4* mp = (const float4*)(s2pm + (size_t)(b * CCH + t) * 64);
    float s = 0.f, m = -3.402823466e38f;
    #pragma unroll
    for (int i = 0; i < 16; i++) {
      float4 a = sp[i]; s += a.x + a.y + a.z + a.w;
      float4 c = mp[i]; m = fmaxf(m, fmaxf(fmaxf(c.x, c.y), fmaxf(c.z, c.w)));
    }
    wsm[t] = s / (float)LL + m;
  }
  __syncthreads();
  if (t < QQ) {
    float a = 0.f;
    for (int c = 0; c < CCH; c++) a += wsm[c] * fc1[t * CCH + c];
    hid[t] = fmaxf(a, 0.f);
  }
  __syncthreads();
  float w2v = 0.f;
  if (t < CCH) {
    float a = 0.f;
    #pragma unroll
    for (int q = 0; q < QQ; q++) a += hid[q] * fc2[t * QQ + q];
    w2v = 1.f / (1.f + __expf(-a));
  }
  __syncthreads();
  if (t < CCH) wsm[t] = w2v;
  __syncthreads();
  for (int i = t; i < 96 * 16; i += 256) {
    int c = i >> 4, q = i & 15;
    float4 v = *(const float4*)(y2 + ((size_t)b * CCH + c) * LL + p0 + q * 4);
    fs[q * 4 + 0][c] = v.x; fs[q * 4 + 1][c] = v.y;
    fs[q * 4 + 2][c] = v.z; fs[q * 4 + 3][c] = v.w;
  }
  for (int i = t; i < 48 * 24; i += 256) {
    int row = i / 24, q = i % 24;
    float4 wv = *(const float4*)(pw + (size_t)(oc0 + row) * CCH + q * 4);
    ((float4*)wbuf)[i] = make_float4(wv.x * wsm[q * 4], wv.y * wsm[q * 4 + 1],
                                     wv.z * wsm[q * 4 + 2], wv.w * wsm[q * 4 + 3]);
  }
  __syncthreads();
  int px = t & 63;
  int cg2 = __builtin_amdgcn_readfirstlane(t >> 6);
  float acc[12];
  #pragma unroll
  for (int j = 0; j < 12; j++) acc[j] = 0.f;
  for (int c4 = 0; c4 < 24; c4++) {
    float4 xv = *(const float4*)(&fs[px][c4 * 4]);
    #pragma unroll
    for (int j = 0; j < 12; j++) {
      float4 wv = *(const float4*)(&wbuf[(cg2 * 12 + j) * 96 + c4 * 4]);
      acc[j] = fmaf(xv.x, wv.x, fmaf(xv.y, wv.y, fmaf(xv.z, wv.z, fmaf(xv.w, wv.w, acc[j]))));
    }
  }
  __syncthreads();
  float* ot = &fs[0][0];
  #pragma unroll
  for (int j = 0; j < 12; j++) ot[px * 49 + cg2 * 12 + j] = acc[j];
  __syncthreads();
  for (int i = t; i < 48 * 64; i += 256) {
    int o = i >> 6, p2 = i & 63;
    size_t oi = ((size_t)b * CCH + oc0 + o) * LL + p0 + p2;
    out[oi] = x[oi] + pb[oc0 + o] + ot[p2 * 49 + o];
  }
}

extern "C" void kernel_launch(void* const* d_in, const int* in_sizes, int n_in,
                              void* d_out, int out_size, void* d_ws, size_t ws_size,
                              hipStream_t stream) {
  const float* x        = (const float*)d_in[0];
  const float* arf_w1   = (const float*)d_in[1];
  const float* arf_b1   = (const float*)d_in[2];
  const float* arf_w2   = (const float*)d_in[3];
  const float* arf_b2   = (const float*)d_in[4];
  const float* arf_w3   = (const float*)d_in[5];
  const float* arf_b3   = (const float*)d_in[6];
  const float* arf_w4   = (const float*)d_in[7];
  const float* arf_b4   = (const float*)d_in[8];
  const float* fuse_w   = (const float*)d_in[9];
  const float* fuse_b   = (const float*)d_in[10];
  const float* edge_w   = (const float*)d_in[11];
  const float* enh_w1   = (const float*)d_in[12];
  const float* enh_b1   = (const float*)d_in[13];
  const float* bn_g     = (const float*)d_in[14];
  const float* bn_b     = (const float*)d_in[15];
  const float* enh_w2   = (const float*)d_in[16];
  const float* enh_b2   = (const float*)d_in[17];
  const float* pre_fc1  = (const float*)d_in[18];
  const float* pre_fc2  = (const float*)d_in[19];
  const float* norm_g   = (const float*)d_in[20];
  const float* norm_b   = (const float*)d_in[21];
  const float* in_proj_w= (const float*)d_in[22];
  const float* ss_conv_w= (const float*)d_in[23];
  const float* ss_conv_b= (const float*)d_in[24];
  const float* x_proj_w = (const float*)d_in[25];
  const float* dt_w     = (const float*)d_in[26];
  const float* dt_b     = (const float*)d_in[27];
  const float* A_logs   = (const float*)d_in[28];
  const float* Ds       = (const float*)d_in[29];
  const float* out_ng   = (const float*)d_in[30];
  const float* out_nb   = (const float*)d_in[31];
  const float* out_proj_w = (const float*)d_in[32];
  const float* post_fc1 = (const float*)d_in[33];
  const float* post_fc2 = (const float*)d_in[34];
  const float* proj_w   = (const float*)d_in[35];
  const float* proj_b   = (const float*)d_in[36];

  float* ws = (float*)d_ws;
  float* fbuf  = ws + OFF_F;
  float* hbuf  = ws + OFF_H;
  float* ebuf  = ws + OFF_E;
  float* e1ps  = ws + OFF_E1PS;
  float* e1p2  = ws + OFF_E1P2;
  float* xmbuf = ws + OFF_XM;
  float* zbuf  = ws + OFF_Z;
  float* xcbuf = ws + OFF_XC;
  float* dtrbuf= ws + OFF_DTS;
  float* bcbuf = ws + OFF_BC;
  float* ykbuf = ws + OFF_YK;
  float* y2buf = ws + OFF_Y2;
  float* hlbuf = ws + OFF_HL;
  float* sdbuf = ws + OFF_SD;
  float* hinbuf= ws + OFF_HIN;
  float* s1ps  = ws + OFF_S1PS;
  float* s1pm  = ws + OFF_S1PM;
  float* s2ps  = ws + OFF_S2PS;
  float* s2pm  = ws + OFF_S2PM;

  k_arf<<<3072, 256, 0, stream>>>(x, arf_w1, arf_b1, arf_w2, arf_b2, arf_w3, arf_b3, arf_w4, arf_b4, fbuf);
  k_fuse<<<dim3(128, 2), 256, 0, stream>>>(fbuf, fuse_w, fuse_b, hbuf);
  k_edge<<<3072, 256, 0, stream>>>(hbuf, edge_w, fbuf);   // edge reuses fbuf
  k_e1<<<768, 256, 0, stream>>>(fbuf, enh_w1, enh_b1, ebuf, e1ps, e1p2);
  k_enh<<<3072, 256, 0, stream>>>(ebuf, e1ps, e1p2, bn_g, bn_b, enh_w2, enh_b2, hbuf, s1ps, s1pm);
  k_inproj<<<dim3(128, 4), 256, 0, stream>>>(hbuf, s1ps, s1pm, pre_fc1, pre_fc2, norm_g, norm_b, in_proj_w, xmbuf, zbuf);
  k_ssconv<<<3072, 256, 0, stream>>>(xmbuf, ss_conv_w, ss_conv_b, xcbuf);
  k_xdbl<<<dim3(LL / XT2, 8), 256, 0, stream>>>(xcbuf, x_proj_w, dtrbuf, bcbuf);
  {
    void* args[] = {(void*)&dtrbuf, (void*)&bcbuf, (void*)&xcbuf, (void*)&A_logs,
                    (void*)&dt_w, (void*)&dt_b, (void*)&hlbuf, (void*)&sdbuf,
                    (void*)&hinbuf, (void*)&ykbuf};
    hipLaunchCooperativeKernel((const void*)k_scan_all, dim3(NCH, 8), dim3(192), args, 0, stream);
  }
  k_outproj<<<dim3(128, 2), 256, 0, stream>>>(ykbuf, xcbuf, Ds, zbuf, out_ng, out_nb, out_proj_w, y2buf, s2ps, s2pm);
  k_final<<<dim3(128, 2), 256, 0, stream>>>(x, y2buf, s2ps, s2pm, post_fc1, post_fc2, proj_w, proj_b, (float*)d_out);
  (void)in_sizes; (void)n_in; (void)out_size; (void)ws_size;
}

// Round 13
// 221.576 us; speedup vs baseline: 1.9534x; 1.9534x over previous
//
#include <hip/hip_runtime.h>
#include <cmath>

#define LL   4096
#define HWD  64
#define CCH  96
#define QQ   24
#define DDI  192
#define NST  16
#define NCH  128     // chunks in scan
#define CLEN 32      // steps per chunk = one LDS tile
#define TSC  32
#define XT2  32      // positions per block in k_xdbl
#define XP   108     // padded LDS stride (96-wide tiles)
#define FP   100     // fuse/final [px][c] stride
#define VP   204     // outproj [px][192ch] stride

// ---------------- workspace layout (floats) ----------------
static const size_t OFF_F    = 0;          // 786432  f (concat arf) -> reused as edge
static const size_t OFF_H    = 786432;     // 786432  h
static const size_t OFF_E    = 1572864;    // 196608  e (raw)
static const size_t OFF_E1PS = 1769472;    // 768
static const size_t OFF_E1P2 = 1770240;    // 768
static const size_t OFF_XM   = 2556736;    // 1572864 xm (B,L,192)
static const size_t OFF_Z    = 4129600;    // 1572864 z  (B,L,192)
static const size_t OFF_XC   = 5702464;    // 1572864 xc (B,L,192)
static const size_t OFF_DTS  = 7275328;    // dtr (B,K,L,6)
static const size_t OFF_BC   = 13566784;   // 1048576 B|C (B,K,L,32)
static const size_t OFF_YK   = 14615360;   // 6291456 yk (B,K,L,192)
static const size_t OFF_Y2   = 22528832;   // 786432  y2 (B,96,L)
static const size_t OFF_HL   = 23315264;   // 3145728
static const size_t OFF_SD   = 26460992;   // 196608
static const size_t OFF_HIN  = 26657600;   // 3145728
static const size_t OFF_S1PS = 29803328;   // 192*16
static const size_t OFF_S1PM = 29806400;   // 192*16
static const size_t OFF_S2PS = 29809472;   // 192*64
static const size_t OFF_S2PM = 29821760;   // 192*64

static __device__ __forceinline__ int map_k(int k, int l) {
  int ll = (k & 2) ? (LL - 1 - l) : l;
  return (k & 1) ? (((ll & 63) << 6) | (ll >> 6)) : ll;
}

// ---------------- K1: ARF grouped dilated convs ----------------
__global__ __launch_bounds__(256) void k_arf(const float* __restrict__ x,
    const float* __restrict__ w1, const float* __restrict__ b1,
    const float* __restrict__ w2, const float* __restrict__ b2,
    const float* __restrict__ w3, const float* __restrict__ b3,
    const float* __restrict__ w4, const float* __restrict__ b4,
    float* __restrict__ f) {
  int idx = blockIdx.x * 256 + threadIdx.x;
  int p = idx & (LL - 1);
  int oc = __builtin_amdgcn_readfirstlane((idx >> 12) % CCH);
  int b  = __builtin_amdgcn_readfirstlane(idx / (CCH * LL));
  int i = oc / QQ, q = oc % QQ;
  int dil = 1 << i;
  const float* w  = (i == 0 ? w1 : i == 1 ? w2 : i == 2 ? w3 : w4) + q * 36;
  const float* bb = (i == 0 ? b1 : i == 1 ? b2 : i == 2 ? b3 : b4);
  int yy0 = p >> 6, xx0 = p & 63;
  float acc = bb[q];
  const float* xin = x + ((size_t)b * CCH + q * 4) * LL;
  #pragma unroll
  for (int ky = 0; ky < 3; ky++) {
    int yy = yy0 + (ky - 1) * dil;
    if (yy < 0 || yy >= HWD) continue;
    #pragma unroll
    for (int kx = 0; kx < 3; kx++) {
      int xx = xx0 + (kx - 1) * dil;
      if (xx < 0 || xx >= HWD) continue;
      int pp = (yy << 6) + xx;
      #pragma unroll
      for (int ci = 0; ci < 4; ci++)
        acc += w[ci * 9 + ky * 3 + kx] * xin[(size_t)ci * LL + pp];
    }
  }
  f[idx] = acc;
}

// ---------------- K2: fuse 1x1 (96->96), LDS-tiled GEMM ----------------
__global__ __launch_bounds__(256) void k_fuse(const float* __restrict__ f,
    const float* __restrict__ fw, const float* __restrict__ fb, float* __restrict__ h) {
  int pix0 = blockIdx.x * 64;
  int oc0 = blockIdx.y * 48;
  int b = pix0 >> 12, p0 = pix0 & (LL - 1);
  int t = threadIdx.x;
  __shared__ float fs[64][FP];
  __shared__ float wbuf[48 * 96];
  for (int i = t; i < 96 * 16; i += 256) {
    int c = i >> 4, q = i & 15;
    float4 v = *(const float4*)(f + ((size_t)b * CCH + c) * LL + p0 + q * 4);
    fs[q * 4 + 0][c] = v.x; fs[q * 4 + 1][c] = v.y;
    fs[q * 4 + 2][c] = v.z; fs[q * 4 + 3][c] = v.w;
  }
  {
    const float4* src = (const float4*)(fw + (size_t)oc0 * CCH);
    float4* dst = (float4*)wbuf;
    for (int i = t; i < 48 * 24; i += 256) dst[i] = src[i];
  }
  __syncthreads();
  int px = t & 63;
  int cg2 = __builtin_amdgcn_readfirstlane(t >> 6);
  float acc[12];
  #pragma unroll
  for (int j = 0; j < 12; j++) acc[j] = 0.f;
  for (int c4 = 0; c4 < 24; c4++) {
    float4 xv = *(const float4*)(&fs[px][c4 * 4]);
    #pragma unroll
    for (int j = 0; j < 12; j++) {
      float4 wv = *(const float4*)(&wbuf[(cg2 * 12 + j) * 96 + c4 * 4]);
      acc[j] = fmaf(xv.x, wv.x, fmaf(xv.y, wv.y, fmaf(xv.z, wv.z, fmaf(xv.w, wv.w, acc[j]))));
    }
  }
  __syncthreads();
  float* ot = &fs[0][0];
  #pragma unroll
  for (int j = 0; j < 12; j++) ot[px * 49 + cg2 * 12 + j] = acc[j];
  __syncthreads();
  for (int i = t; i < 48 * 64; i += 256) {
    int o = i >> 6, p2 = i & 63;
    h[((size_t)b * CCH + oc0 + o) * LL + p0 + p2] = ot[p2 * 49 + o] + fb[oc0 + o];
  }
}

// ---------------- K3: depthwise 3x3 (edge) ----------------
__global__ __launch_bounds__(256) void k_edge(const float* __restrict__ h,
    const float* __restrict__ ew, float* __restrict__ edge) {
  int idx = blockIdx.x * 256 + threadIdx.x;
  int p = idx & (LL - 1);
  int c = __builtin_amdgcn_readfirstlane((idx >> 12) % CCH);
  int b = __builtin_amdgcn_readfirstlane(idx / (CCH * LL));
  int yy0 = p >> 6, xx0 = p & 63;
  const float* w = ew + c * 9;
  const float* hr = h + ((size_t)b * CCH + c) * LL;
  float acc = 0.f;
  #pragma unroll
  for (int ky = 0; ky < 3; ky++) {
    int yy = yy0 + ky - 1;
    if (yy < 0 || yy >= HWD) continue;
    #pragma unroll
    for (int kx = 0; kx < 3; kx++) {
      int xx = xx0 + kx - 1;
      if (xx < 0 || xx >= HWD) continue;
      acc += w[ky * 3 + kx] * hr[(yy << 6) + xx];
    }
  }
  edge[idx] = acc;
}

// ---------------- K4: 1x1 96->24 + BN partials ----------------
__global__ __launch_bounds__(256) void k_e1(const float* __restrict__ edge,
    const float* __restrict__ w, const float* __restrict__ bias, float* __restrict__ e,
    float* __restrict__ e1ps, float* __restrict__ e1p2) {
  int tid = threadIdx.x;
  int idx = blockIdx.x * 256 + tid;
  int p = idx & (LL - 1);
  int q = __builtin_amdgcn_readfirstlane((idx >> 12) % QQ);
  int b = __builtin_amdgcn_readfirstlane(idx / (QQ * LL));
  const float* er = edge + (size_t)b * CCH * LL + p;
  const float* wr = w + q * CCH;
  float acc = bias[q];
  for (int c = 0; c < CCH; c++) acc += wr[c] * er[(size_t)c * LL];
  e[idx] = acc;
  __shared__ float rs[256], r2[256];
  rs[tid] = acc; r2[tid] = acc * acc; __syncthreads();
  for (int st = 128; st > 0; st >>= 1) {
    if (tid < st) { rs[tid] += rs[tid + st]; r2[tid] += r2[tid + st]; }
    __syncthreads();
  }
  if (tid == 0) { e1ps[blockIdx.x] = rs[0]; e1p2[blockIdx.x] = r2[0]; }
}

// ---------------- K6: BN-reduce + enh gate + s1 partials ----------------
__global__ __launch_bounds__(256) void k_enh(const float* __restrict__ e,
    const float* __restrict__ e1ps, const float* __restrict__ e1p2,
    const float* __restrict__ bn_g, const float* __restrict__ bn_b,
    const float* __restrict__ w2, const float* __restrict__ b2,
    float* __restrict__ h, float* __restrict__ s1ps, float* __restrict__ s1pm) {
  int tid = threadIdx.x;
  __shared__ float bns[QQ], bnsh[QQ];
  if (tid < QQ) {
    float s = 0.f, s2 = 0.f;
    #pragma unroll
    for (int b2 = 0; b2 < 2; b2++)
      for (int i = 0; i < 16; i++) {
        int pi = (b2 * QQ + tid) * 16 + i;
        s += e1ps[pi]; s2 += e1p2[pi];
      }
    float mu = s / (2.f * LL);
    float var = s2 / (2.f * LL) - mu * mu;
    float sc = bn_g[tid] * rsqrtf(var + 1e-5f);
    bns[tid] = sc;
    bnsh[tid] = bn_b[tid] - mu * sc;
  }
  __syncthreads();
  int idx = blockIdx.x * 256 + tid;
  int p = idx & (LL - 1);
  int o = __builtin_amdgcn_readfirstlane((idx >> 12) % CCH);
  int b = __builtin_amdgcn_readfirstlane(idx / (CCH * LL));
  const float* er = e + (size_t)b * QQ * LL + p;
  const float* wr = w2 + o * QQ;
  float acc = b2[o];
  #pragma unroll
  for (int q = 0; q < QQ; q++) {
    float en = fmaxf(er[(size_t)q * LL] * bns[q] + bnsh[q], 0.f);
    acc += wr[q] * en;
  }
  float sig = 1.f / (1.f + __expf(-acc));
  float val = h[idx] * (1.f + sig);
  h[idx] = val;
  __shared__ float rsum[256], rmax[256];
  rsum[tid] = val; rmax[tid] = val; __syncthreads();
  for (int st = 128; st > 0; st >>= 1) {
    if (tid < st) { rsum[tid] += rsum[tid + st]; rmax[tid] = fmaxf(rmax[tid], rmax[tid + st]); }
    __syncthreads();
  }
  if (tid == 0) {
    int row = blockIdx.x >> 4, blk = blockIdx.x & 15;
    s1ps[row * 16 + blk] = rsum[0];
    s1pm[row * 16 + blk] = rmax[0];
  }
}

// ---------------- K8: fused s1-reduce + recal-FC + recal + LN + in_proj ----------------
__global__ __launch_bounds__(256) void k_inproj(const float* __restrict__ h,
    const float* __restrict__ s1ps, const float* __restrict__ s1pm,
    const float* __restrict__ fc1, const float* __restrict__ fc2,
    const float* __restrict__ ng, const float* __restrict__ nb,
    const float* __restrict__ W, float* __restrict__ xm, float* __restrict__ z) {
  int pix0 = blockIdx.x * 64;
  int oc0 = blockIdx.y * CCH;
  int b = pix0 >> 12, p0 = pix0 & (LL - 1);
  int t = threadIdx.x;
  __shared__ float xs[64][XP];
  __shared__ float wbuf[CCH * CCH];
  __shared__ float wsm[CCH];
  __shared__ float hid[QQ];
  __shared__ float ps[64][4], ps2[64][4];
  __shared__ float mu_s[64], rs_s[64];
  if (t < CCH) {
    const float4* sp = (const float4*)(s1ps + (size_t)(b * CCH + t) * 16);
    const float4* mp = (const float4*)(s1pm + (size_t)(b * CCH + t) * 16);
    float s = 0.f, m = -3.402823466e38f;
    #pragma unroll
    for (int i = 0; i < 4; i++) {
      float4 a = sp[i]; s += a.x + a.y + a.z + a.w;
      float4 c = mp[i]; m = fmaxf(m, fmaxf(fmaxf(c.x, c.y), fmaxf(c.z, c.w)));
    }
    wsm[t] = s / (float)LL + m;
  }
  __syncthreads();
  if (t < QQ) {
    float a = 0.f;
    for (int c = 0; c < CCH; c++) a += wsm[c] * fc1[t * CCH + c];
    hid[t] = fmaxf(a, 0.f);
  }
  __syncthreads();
  float w1v = 0.f;
  if (t < CCH) {
    float a = 0.f;
    #pragma unroll
    for (int q = 0; q < QQ; q++) a += hid[q] * fc2[t * QQ + q];
    w1v = 1.f / (1.f + __expf(-a));
  }
  __syncthreads();
  if (t < CCH) wsm[t] = w1v;
  {
    const float4* src = (const float4*)(W + (size_t)oc0 * CCH);
    float4* dst = (float4*)wbuf;
    for (int i = t; i < CCH * 24; i += 256) dst[i] = src[i];
  }
  __syncthreads();
  for (int i = t; i < CCH * 16; i += 256) {
    int c = i >> 4, q = i & 15;
    float w = wsm[c];
    float4 v = *(const float4*)(h + ((size_t)b * CCH + c) * LL + p0 + q * 4);
    xs[q * 4 + 0][c] = v.x * w; xs[q * 4 + 1][c] = v.y * w;
    xs[q * 4 + 2][c] = v.z * w; xs[q * 4 + 3][c] = v.w * w;
  }
  __syncthreads();
  {
    int px = t & 63, qr = t >> 6;
    float s = 0.f, s2 = 0.f;
    #pragma unroll
    for (int j = 0; j < 24; j++) { float v = xs[px][qr * 24 + j]; s += v; s2 += v * v; }
    ps[px][qr] = s; ps2[px][qr] = s2;
  }
  __syncthreads();
  if (t < 64) {
    float ss = ps[t][0] + ps[t][1] + ps[t][2] + ps[t][3];
    float ss2 = ps2[t][0] + ps2[t][1] + ps2[t][2] + ps2[t][3];
    float mu = ss / (float)CCH;
    mu_s[t] = mu;
    rs_s[t] = rsqrtf(ss2 / (float)CCH - mu * mu + 1e-5f);
  }
  __syncthreads();
  for (int i = t; i < 64 * CCH; i += 256) {
    int px = i / CCH, c = i % CCH;
    xs[px][c] = (xs[px][c] - mu_s[px]) * rs_s[px] * ng[c] + nb[c];
  }
  __syncthreads();
  int li = t & 63;
  int cg2 = __builtin_amdgcn_readfirstlane(t >> 6);
  float acc[24];
  #pragma unroll
  for (int j = 0; j < 24; j++) acc[j] = 0.f;
  for (int dq = 0; dq < 24; dq++) {
    float4 xv = *(const float4*)(&xs[li][dq * 4]);
    #pragma unroll
    for (int j = 0; j < 24; j++) {
      float4 wv = *(const float4*)(&wbuf[(cg2 + 4 * j) * CCH + dq * 4]);
      acc[j] = fmaf(xv.x, wv.x, fmaf(xv.y, wv.y, fmaf(xv.z, wv.z, fmaf(xv.w, wv.w, acc[j]))));
    }
  }
  __syncthreads();
  float* ot = &xs[0][0];
  #pragma unroll
  for (int j = 0; j < 24; j++) ot[li * 97 + cg2 + 4 * j] = acc[j];
  __syncthreads();
  float* dst = (oc0 < DDI) ? xm : z;
  int od0 = oc0 % DDI;
  for (int i = t; i < 64 * 96; i += 256) {
    int row = i / 96, c = i % 96;
    dst[(size_t)(pix0 + row) * DDI + od0 + c] = ot[row * 97 + c];
  }
}

// ---------------- K9: depthwise 3x3 + silu, 2 rows/thread ----------------
__global__ __launch_bounds__(256) void k_ssconv(const float* __restrict__ xm,
    const float* __restrict__ w, const float* __restrict__ bias, float* __restrict__ xc) {
  int idx = blockIdx.x * 256 + threadIdx.x;
  int d = idx % DDI;
  int rem = idx / DDI;
  int xx0 = rem & 63;
  int y0 = ((rem >> 6) & 31) * 2;
  int b = idx / (DDI * LL / 2);
  float wv[9];
  #pragma unroll
  for (int i = 0; i < 9; i++) wv[i] = w[d * 9 + i];
  float acc0 = bias[d], acc1 = bias[d];
  const float* xr = xm + (size_t)b * LL * DDI + d;
  #pragma unroll
  for (int ky = -1; ky <= 2; ky++) {
    int yy = y0 + ky;
    if (yy < 0 || yy >= HWD) continue;
    #pragma unroll
    for (int kx = -1; kx <= 1; kx++) {
      int xx = xx0 + kx;
      if (xx < 0 || xx >= HWD) continue;
      float val = xr[(size_t)((yy << 6) + xx) * DDI];
      if (ky <= 1) acc0 += wv[(ky + 1) * 3 + (kx + 1)] * val;
      if (ky >= 0) acc1 += wv[ky * 3 + (kx + 1)] * val;
    }
  }
  size_t o0 = ((size_t)b * LL + (y0 << 6) + xx0) * DDI + d;
  xc[o0] = acc0 / (1.f + __expf(-acc0));
  xc[o0 + 64 * DDI] = acc1 / (1.f + __expf(-acc1));
}

// ---------------- K10: x_proj (192->38) -> dtr + B/C ----------------
__global__ __launch_bounds__(256) void k_xdbl(const float* __restrict__ xc,
    const float* __restrict__ xpw, float* __restrict__ dtr_ws, float* __restrict__ bcb) {
  int lt = blockIdx.x;
  int bk = blockIdx.y;
  int b = bk >> 2, k = bk & 3;
  int t = threadIdx.x;
  __shared__ float xs[XT2][XP];
  __shared__ float wbuf[38 * 96];
  int l0 = lt * XT2;
  int pos = t & 31;
  int cg2 = t >> 5;
  float acc[5];
  #pragma unroll
  for (int j = 0; j < 5; j++) acc[j] = 0.f;
  for (int h = 0; h < 2; h++) {
    __syncthreads();
    for (int i = t; i < XT2 * 24; i += 256) {
      int row = i / 24, dq = i % 24;
      int p = map_k(k, l0 + row);
      *(float4*)(&xs[row][dq * 4]) =
          *(const float4*)(xc + ((size_t)b * LL + p) * DDI + h * 96 + dq * 4);
    }
    for (int i = t; i < 38 * 24; i += 256) {
      int c = i / 24, dq = i % 24;
      *(float4*)(&wbuf[c * 96 + dq * 4]) =
          *(const float4*)(xpw + ((size_t)k * 38 + c) * DDI + h * 96 + dq * 4);
    }
    __syncthreads();
    for (int dq = 0; dq < 24; dq++) {
      float4 xv = *(const float4*)(&xs[pos][dq * 4]);
      #pragma unroll
      for (int j = 0; j < 5; j++) {
        int c = cg2 + 8 * j;
        if (c < 38) {
          float4 wv = *(const float4*)(&wbuf[c * 96 + dq * 4]);
          acc[j] = fmaf(xv.x, wv.x, fmaf(xv.y, wv.y, fmaf(xv.z, wv.z, fmaf(xv.w, wv.w, acc[j]))));
        }
      }
    }
  }
  #pragma unroll
  for (int j = 0; j < 5; j++) {
    int c = cg2 + 8 * j;
    if (c < 6) dtr_ws[((size_t)bk * LL + l0 + pos) * 6 + c] = acc[j];
    else if (c < 38) bcb[((size_t)bk * LL + l0 + pos) * 32 + (c - 6)] = acc[j];
  }
}

// ---------------- K11: chunked selective scan (rank-6 dt on the fly) ----------------
template <int PASS>
__global__ __launch_bounds__(192) void k_scan(const float* __restrict__ dtr_ws,
    const float* __restrict__ bcb, const float* __restrict__ xc,
    const float* __restrict__ A_logs, const float* __restrict__ dtw,
    const float* __restrict__ dtb, float* __restrict__ hl, float* __restrict__ sd,
    const float* __restrict__ hin, float* __restrict__ yk) {
  int ch = blockIdx.x, bk = blockIdx.y;
  int b = bk >> 2, k = bk & 3;
  int d = threadIdx.x;
  __shared__ float u_s[TSC][DDI];
  __shared__ float bcs[TSC][32];
  __shared__ float dtr_s[TSC][6];
  float Av[NST];
  #pragma unroll
  for (int n = 0; n < NST; n++) Av[n] = -__expf(A_logs[(size_t)(k * DDI + d) * NST + n]);
  bool pw = true;
  #pragma unroll
  for (int n = 1; n < NST; n++) pw = pw && (fabsf(Av[n] - (float)(n + 1) * Av[0]) <= 1e-3f * (n + 1));
  float wdt[6];
  #pragma unroll
  for (int r = 0; r < 6; r++) wdt[r] = dtw[((size_t)(k * DDI + d)) * 6 + r];
  float bdt = dtb[k * DDI + d];
  float h[NST];
  if (PASS == 0) {
    #pragma unroll
    for (int n = 0; n < NST; n++) h[n] = 0.f;
  } else {
    const float* hp = hin + ((size_t)(bk * DDI + d) * NCH + ch) * NST;
    #pragma unroll
    for (int n = 0; n < NST; n++) h[n] = hp[n];
  }
  float sumdt = 0.f;
  int l0 = ch * CLEN;
  {
    for (int i = d; i < TSC * (DDI / 4); i += 192) {
      int row = i / (DDI / 4), q = i % (DDI / 4);
      int p = map_k(k, l0 + row);
      ((float4*)u_s)[i] = *(const float4*)(xc + ((size_t)b * LL + p) * DDI + q * 4);
    }
    {
      const float4* src = (const float4*)(bcb + ((size_t)bk * LL + l0) * 32);
      float4* dst = (float4*)bcs;
      for (int i = d; i < TSC * 32 / 4; i += 192) dst[i] = src[i];
    }
    for (int i = d; i < TSC * 6; i += 192)
      ((float*)dtr_s)[i] = dtr_ws[((size_t)bk * LL + l0) * 6 + i];
    __syncthreads();
    for (int tt = 0; tt < TSC; tt++) {
      float a = bdt;
      #pragma unroll
      for (int r = 0; r < 6; r++) a = fmaf(wdt[r], dtr_s[tt][r], a);
      float dt = (a > 15.f) ? a : __logf(1.f + __expf(a));
      float u  = u_s[tt][d];
      float dtu = dt * u;
      if (PASS == 0) sumdt += dt;
      float eA[NST];
      if (pw) {
        float E = __expf(dt * Av[0]);
        float en = 1.f;
        #pragma unroll
        for (int n = 0; n < NST; n++) { en *= E; eA[n] = en; }
      } else {
        #pragma unroll
        for (int n = 0; n < NST; n++) eA[n] = __expf(dt * Av[n]);
      }
      float y = 0.f;
      #pragma unroll
      for (int n = 0; n < NST; n++) {
        h[n] = eA[n] * h[n] + dtu * bcs[tt][n];
        y += h[n] * bcs[tt][16 + n];
      }
      if (PASS == 1) {
        int p = map_k(k, l0 + tt);
        yk[((size_t)bk * LL + p) * DDI + d] = y;
      }
    }
  }
  if (PASS == 0) {
    float* hp = hl + ((size_t)(bk * DDI + d) * NCH + ch) * NST;
    #pragma unroll
    for (int n = 0; n < NST; n++) hp[n] = h[n];
    sd[(size_t)(bk * DDI + d) * NCH + ch] = sumdt;
  }
}

// ---------------- K11b: chunk-carry propagation ----------------
__global__ __launch_bounds__(256) void k_carry(const float* __restrict__ A_logs,
    const float* __restrict__ hl, const float* __restrict__ sd, float* __restrict__ hin) {
  int idx = blockIdx.x * 256 + threadIdx.x;
  int n = idx & 15;
  int d = (idx >> 4) % DDI;
  int bk = idx / (DDI * NST);
  int k = bk & 3;
  float Aval = -__expf(A_logs[(size_t)(k * DDI + d) * NST + n]);
  float h = 0.f;
  size_t base = (size_t)(bk * DDI + d) * NCH;
  for (int ch = 0; ch < NCH; ch++) {
    hin[(base + ch) * NST + n] = h;
    h = __expf(Aval * sd[base + ch]) * h + hl[(base + ch) * NST + n];
  }
}

// ---------------- K12: fused combine+LN+gate + out_proj + s2 partials ----------------
__global__ __launch_bounds__(256) void k_outproj(const float* __restrict__ yk,
    const float* __restrict__ xc, const float* __restrict__ Ds, const float* __restrict__ z,
    const float* __restrict__ ong, const float* __restrict__ onb,
    const float* __restrict__ W, float* __restrict__ y2,
    float* __restrict__ s2ps, float* __restrict__ s2pm) {
  int pix0 = blockIdx.x * 64;
  int oc0 = blockIdx.y * 48;
  int b = pix0 >> 12, p0 = pix0 & (LL - 1);
  int t = threadIdx.x;
  __shared__ float xs[64][VP];
  __shared__ float wbuf[48 * 96];
  __shared__ float dsum[DDI];
  __shared__ float ps[64][4], ps2[64][4];
  __shared__ float mu_s[64], rs_s[64];
  if (t < 48) {
    float4 a  = *(const float4*)(Ds + t * 4);
    float4 c1 = *(const float4*)(Ds + DDI + t * 4);
    float4 c2 = *(const float4*)(Ds + 2 * DDI + t * 4);
    float4 c3 = *(const float4*)(Ds + 3 * DDI + t * 4);
    *(float4*)(&dsum[t * 4]) = make_float4(a.x + c1.x + c2.x + c3.x, a.y + c1.y + c2.y + c3.y,
                                           a.z + c1.z + c2.z + c3.z, a.w + c1.w + c2.w + c3.w);
  }
  __syncthreads();
  int px = t & 63, qr = t >> 6;
  int p = p0 + px;
  size_t pb = ((size_t)b * LL + p) * DDI;
  size_t yb = ((size_t)b * 4 * LL + p) * DDI;
  {
    float s = 0.f, s2 = 0.f;
    #pragma unroll
    for (int j = 0; j < 12; j++) {
      int c = (qr * 12 + j) * 4;
      float4 y0 = *(const float4*)(yk + yb + c);
      float4 y1 = *(const float4*)(yk + yb + (size_t)LL * DDI + c);
      float4 y2v = *(const float4*)(yk + yb + 2ul * LL * DDI + c);
      float4 y3 = *(const float4*)(yk + yb + 3ul * LL * DDI + c);
      float4 u = *(const float4*)(xc + pb + c);
      float4 dv = *(const float4*)(&dsum[c]);
      float4 v;
      v.x = y0.x + y1.x + y2v.x + y3.x + dv.x * u.x;
      v.y = y0.y + y1.y + y2v.y + y3.y + dv.y * u.y;
      v.z = y0.z + y1.z + y2v.z + y3.z + dv.z * u.z;
      v.w = y0.w + y1.w + y2v.w + y3.w + dv.w * u.w;
      *(float4*)(&xs[px][c]) = v;
      s += v.x + v.y + v.z + v.w;
      s2 += v.x * v.x + v.y * v.y + v.z * v.z + v.w * v.w;
    }
    ps[px][qr] = s; ps2[px][qr] = s2;
  }
  __syncthreads();
  if (t < 64) {
    float ss = ps[t][0] + ps[t][1] + ps[t][2] + ps[t][3];
    float ss2 = ps2[t][0] + ps2[t][1] + ps2[t][2] + ps2[t][3];
    float mu = ss / (float)DDI;
    mu_s[t] = mu;
    rs_s[t] = rsqrtf(ss2 / (float)DDI - mu * mu + 1e-5f);
  }
  __syncthreads();
  {
    float mu = mu_s[px], rs = rs_s[px];
    #pragma unroll
    for (int j = 0; j < 12; j++) {
      int c = (qr * 12 + j) * 4;
      float4 v = *(const float4*)(&xs[px][c]);
      float4 zz = *(const float4*)(z + pb + c);
      float4 og = *(const float4*)(ong + c);
      float4 ob = *(const float4*)(onb + c);
      float4 gv;
      gv.x = ((v.x - mu) * rs * og.x + ob.x) * (zz.x / (1.f + __expf(-zz.x)));
      gv.y = ((v.y - mu) * rs * og.y + ob.y) * (zz.y / (1.f + __expf(-zz.y)));
      gv.z = ((v.z - mu) * rs * og.z + ob.z) * (zz.z / (1.f + __expf(-zz.z)));
      gv.w = ((v.w - mu) * rs * og.w + ob.w) * (zz.w / (1.f + __expf(-zz.w)));
      *(float4*)(&xs[px][c]) = gv;
    }
  }
  int li = px;
  int cg2 = __builtin_amdgcn_readfirstlane(qr);
  float acc[12];
  #pragma unroll
  for (int j = 0; j < 12; j++) acc[j] = 0.f;
  for (int hh = 0; hh < 2; hh++) {
    __syncthreads();
    for (int i = t; i < 48 * 24; i += 256) {
      int c = i / 24, dq = i % 24;
      *(float4*)(&wbuf[c * 96 + dq * 4]) =
          *(const float4*)(W + (size_t)(oc0 + c) * DDI + hh * 96 + dq * 4);
    }
    __syncthreads();
    for (int dq = 0; dq < 24; dq++) {
      float4 xv = *(const float4*)(&xs[li][hh * 96 + dq * 4]);
      #pragma unroll
      for (int j = 0; j < 12; j++) {
        float4 wv = *(const float4*)(&wbuf[(cg2 + 4 * j) * 96 + dq * 4]);
        acc[j] = fmaf(xv.x, wv.x, fmaf(xv.y, wv.y, fmaf(xv.z, wv.z, fmaf(xv.w, wv.w, acc[j]))));
      }
    }
  }
  int lane = t & 63;
  #pragma unroll
  for (int j = 0; j < 12; j++) {
    float sv = acc[j], mv = acc[j];
    #pragma unroll
    for (int o = 32; o > 0; o >>= 1) {
      sv += __shfl_xor(sv, o);
      mv = fmaxf(mv, __shfl_xor(mv, o));
    }
    if (lane == 0) {
      int oc = oc0 + cg2 + 4 * j;
      int tile = blockIdx.x & 63;
      s2ps[(size_t)(b * CCH + oc) * 64 + tile] = sv;
      s2pm[(size_t)(b * CCH + oc) * 64 + tile] = mv;
    }
  }
  __syncthreads();
  float* ot = &xs[0][0];
  #pragma unroll
  for (int j = 0; j < 12; j++) ot[li * 49 + cg2 + 4 * j] = acc[j];
  __syncthreads();
  for (int i = t; i < 48 * 64; i += 256) {
    int o = i / 64, pi = i % 64;
    y2[((size_t)b * CCH + oc0 + o) * LL + p0 + pi] = ot[pi * 49 + o];
  }
}

// ---------------- K14: fused s2-reduce + recal-FC + recal + proj + residual ----------------
__global__ __launch_bounds__(256) void k_final(const float* __restrict__ x,
    const float* __restrict__ y2, const float* __restrict__ s2ps, const float* __restrict__ s2pm,
    const float* __restrict__ fc1, const float* __restrict__ fc2,
    const float* __restrict__ pw, const float* __restrict__ pb, float* __restrict__ out) {
  int pix0 = blockIdx.x * 64;
  int oc0 = blockIdx.y * 48;
  int b = pix0 >> 12, p0 = pix0 & (LL - 1);
  int t = threadIdx.x;
  __shared__ float fs[64][FP];
  __shared__ float wbuf[48 * 96];
  __shared__ float wsm[CCH];
  __shared__ float hid[QQ];
  if (t < CCH) {
    const float4* sp = (const float4*)(s2ps + (size_t)(b * CCH + t) * 64);
    const float4* mp = (const float4*)(s2pm + (size_t)(b * CCH + t) * 64);
    float s = 0.f, m = -3.402823466e38f;
    #pragma unroll
    for (int i = 0; i < 16; i++) {
      float4 a = sp[i]; s += a.x + a.y + a.z + a.w;
      float4 c = mp[i]; m = fmaxf(m, fmaxf(fmaxf(c.x, c.y), fmaxf(c.z, c.w)));
    }
    wsm[t] = s / (float)LL + m;
  }
  __syncthreads();
  if (t < QQ) {
    float a = 0.f;
    for (int c = 0; c < CCH; c++) a += wsm[c] * fc1[t * CCH + c];
    hid[t] = fmaxf(a, 0.f);
  }
  __syncthreads();
  float w2v = 0.f;
  if (t < CCH) {
    float a = 0.f;
    #pragma unroll
    for (int q = 0; q < QQ; q++) a += hid[q] * fc2[t * QQ + q];
    w2v = 1.f / (1.f + __expf(-a));
  }
  __syncthreads();
  if (t < CCH) wsm[t] = w2v;
  __syncthreads();
  for (int i = t; i < 96 * 16; i += 256) {
    int c = i >> 4, q = i & 15;
    float4 v = *(const float4*)(y2 + ((size_t)b * CCH + c) * LL + p0 + q * 4);
    fs[q * 4 + 0][c] = v.x; fs[q * 4 + 1][c] = v.y;
    fs[q * 4 + 2][c] = v.z; fs[q * 4 + 3][c] = v.w;
  }
  for (int i = t; i < 48 * 24; i += 256) {
    int row = i / 24, q = i % 24;
    float4 wv = *(const float4*)(pw + (size_t)(oc0 + row) * CCH + q * 4);
    ((float4*)wbuf)[i] = make_float4(wv.x * wsm[q * 4], wv.y * wsm[q * 4 + 1],
                                     wv.z * wsm[q * 4 + 2], wv.w * wsm[q * 4 + 3]);
  }
  __syncthreads();
  int px = t & 63;
  int cg2 = __builtin_amdgcn_readfirstlane(t >> 6);
  float acc[12];
  #pragma unroll
  for (int j = 0; j < 12; j++) acc[j] = 0.f;
  for (int c4 = 0; c4 < 24; c4++) {
    float4 xv = *(const float4*)(&fs[px][c4 * 4]);
    #pragma unroll
    for (int j = 0; j < 12; j++) {
      float4 wv = *(const float4*)(&wbuf[(cg2 * 12 + j) * 96 + c4 * 4]);
      acc[j] = fmaf(xv.x, wv.x, fmaf(xv.y, wv.y, fmaf(xv.z, wv.z, fmaf(xv.w, wv.w, acc[j]))));
    }
  }
  __syncthreads();
  float* ot = &fs[0][0];
  #pragma unroll
  for (int j = 0; j < 12; j++) ot[px * 49 + cg2 * 12 + j] = acc[j];
  __syncthreads();
  for (int i = t; i < 48 * 64; i += 256) {
    int o = i >> 6, p2 = i & 63;
    size_t oi = ((size_t)b * CCH + oc0 + o) * LL + p0 + p2;
    out[oi] = x[oi] + pb[oc0 + o] + ot[p2 * 49 + o];
  }
}

extern "C" void kernel_launch(void* const* d_in, const int* in_sizes, int n_in,
                              void* d_out, int out_size, void* d_ws, size_t ws_size,
                              hipStream_t stream) {
  const float* x        = (const float*)d_in[0];
  const float* arf_w1   = (const float*)d_in[1];
  const float* arf_b1   = (const float*)d_in[2];
  const float* arf_w2   = (const float*)d_in[3];
  const float* arf_b2   = (const float*)d_in[4];
  const float* arf_w3   = (const float*)d_in[5];
  const float* arf_b3   = (const float*)d_in[6];
  const float* arf_w4   = (const float*)d_in[7];
  const float* arf_b4   = (const float*)d_in[8];
  const float* fuse_w   = (const float*)d_in[9];
  const float* fuse_b   = (const float*)d_in[10];
  const float* edge_w   = (const float*)d_in[11];
  const float* enh_w1   = (const float*)d_in[12];
  const float* enh_b1   = (const float*)d_in[13];
  const float* bn_g     = (const float*)d_in[14];
  const float* bn_b     = (const float*)d_in[15];
  const float* enh_w2   = (const float*)d_in[16];
  const float* enh_b2   = (const float*)d_in[17];
  const float* pre_fc1  = (const float*)d_in[18];
  const float* pre_fc2  = (const float*)d_in[19];
  const float* norm_g   = (const float*)d_in[20];
  const float* norm_b   = (const float*)d_in[21];
  const float* in_proj_w= (const float*)d_in[22];
  const float* ss_conv_w= (const float*)d_in[23];
  const float* ss_conv_b= (const float*)d_in[24];
  const float* x_proj_w = (const float*)d_in[25];
  const float* dt_w     = (const float*)d_in[26];
  const float* dt_b     = (const float*)d_in[27];
  const float* A_logs   = (const float*)d_in[28];
  const float* Ds       = (const float*)d_in[29];
  const float* out_ng   = (const float*)d_in[30];
  const float* out_nb   = (const float*)d_in[31];
  const float* out_proj_w = (const float*)d_in[32];
  const float* post_fc1 = (const float*)d_in[33];
  const float* post_fc2 = (const float*)d_in[34];
  const float* proj_w   = (const float*)d_in[35];
  const float* proj_b   = (const float*)d_in[36];

  float* ws = (float*)d_ws;
  float* fbuf  = ws + OFF_F;
  float* hbuf  = ws + OFF_H;
  float* ebuf  = ws + OFF_E;
  float* e1ps  = ws + OFF_E1PS;
  float* e1p2  = ws + OFF_E1P2;
  float* xmbuf = ws + OFF_XM;
  float* zbuf  = ws + OFF_Z;
  float* xcbuf = ws + OFF_XC;
  float* dtrbuf= ws + OFF_DTS;
  float* bcbuf = ws + OFF_BC;
  float* ykbuf = ws + OFF_YK;
  float* y2buf = ws + OFF_Y2;
  float* hlbuf = ws + OFF_HL;
  float* sdbuf = ws + OFF_SD;
  float* hinbuf= ws + OFF_HIN;
  float* s1ps  = ws + OFF_S1PS;
  float* s1pm  = ws + OFF_S1PM;
  float* s2ps  = ws + OFF_S2PS;
  float* s2pm  = ws + OFF_S2PM;

  k_arf<<<3072, 256, 0, stream>>>(x, arf_w1, arf_b1, arf_w2, arf_b2, arf_w3, arf_b3, arf_w4, arf_b4, fbuf);
  k_fuse<<<dim3(128, 2), 256, 0, stream>>>(fbuf, fuse_w, fuse_b, hbuf);
  k_edge<<<3072, 256, 0, stream>>>(hbuf, edge_w, fbuf);   // edge reuses fbuf
  k_e1<<<768, 256, 0, stream>>>(fbuf, enh_w1, enh_b1, ebuf, e1ps, e1p2);
  k_enh<<<3072, 256, 0, stream>>>(ebuf, e1ps, e1p2, bn_g, bn_b, enh_w2, enh_b2, hbuf, s1ps, s1pm);
  k_inproj<<<dim3(128, 4), 256, 0, stream>>>(hbuf, s1ps, s1pm, pre_fc1, pre_fc2, norm_g, norm_b, in_proj_w, xmbuf, zbuf);
  k_ssconv<<<3072, 256, 0, stream>>>(xmbuf, ss_conv_w, ss_conv_b, xcbuf);
  k_xdbl<<<dim3(LL / XT2, 8), 256, 0, stream>>>(xcbuf, x_proj_w, dtrbuf, bcbuf);
  k_scan<0><<<dim3(NCH, 8), 192, 0, stream>>>(dtrbuf, bcbuf, xcbuf, A_logs, dt_w, dt_b, hlbuf, sdbuf, nullptr, nullptr);
  k_carry<<<96, 256, 0, stream>>>(A_logs, hlbuf, sdbuf, hinbuf);
  k_scan<1><<<dim3(NCH, 8), 192, 0, stream>>>(dtrbuf, bcbuf, xcbuf, A_logs, dt_w, dt_b, nullptr, nullptr, hinbuf, ykbuf);
  k_outproj<<<dim3(128, 2), 256, 0, stream>>>(ykbuf, xcbuf, Ds, zbuf, out_ng, out_nb, out_proj_w, y2buf, s2ps, s2pm);
  k_final<<<dim3(128, 2), 256, 0, stream>>>(x, y2buf, s2ps, s2pm, post_fc1, post_fc2, proj_w, proj_b, (float*)d_out);
  (void)in_sizes; (void)n_in; (void)out_size; (void)ws_size;
}